// Round 1
// 337.480 us; speedup vs baseline: 1.1385x; 1.1385x over previous
//
#include <hip/hip_runtime.h>
#include <stdint.h>

typedef __bf16 bf16;
typedef __attribute__((ext_vector_type(8))) __bf16 bf16x8;
typedef __attribute__((ext_vector_type(4))) __bf16 bf16x4;
typedef __attribute__((ext_vector_type(4))) float f32x4;

#define LG_D 128

__device__ __forceinline__ void gload_lds16(const void* g, void* l){
  __builtin_amdgcn_global_load_lds(
      (const __attribute__((address_space(1))) void*)g,
      (__attribute__((address_space(3))) void*)l, 16, 0, 0);
}

// ---------------- zero (cnt_in + cnt_out contiguous) ----------------
__global__ void zero_kernel(int* a, int n){
  int i = blockIdx.x * blockDim.x + threadIdx.x;
  if(i < n) a[i] = 0;
}

// ---------------- K1: B granulation (all 4 matrices) + degree histogram ----------------
// granule g=(k8,col): out[g*8+j] = in[k8*8+j][col]; one BK=32 tile = 512
// contiguous granules = 8KB. Pads (k>=Ksrc) are ZERO -> tail/overrun steps
// multiply zero-B, so the GEMM needs no k-guards (uniform vmcnt counts).
// Blocks >= nbig+56 do the edge histogram (independent work, hides its latency).
__global__ void k1_gran_hist(const float* __restrict__ next_h, const float* __restrict__ W_conv,
                             const float* __restrict__ W_fus,  const float* __restrict__ cat_W,
                             bf16* __restrict__ Bg, bf16* __restrict__ Wcg,
                             bf16* __restrict__ Wfg, bf16* __restrict__ catWg,
                             int K, int nbig,
                             const int* __restrict__ src, const int* __restrict__ dst,
                             int* cnt_out, int* cnt_in, int E){
  int b = blockIdx.x;
  const int ngran = nbig + 56;
  if(b >= ngran){
    int e = (b - ngran) * 256 + threadIdx.x;
    if(e < E){
      atomicAdd(&cnt_out[src[e]], 1);
      atomicAdd(&cnt_in[dst[e]], 1);
    }
    return;
  }
  const float* srcp; bf16* dstp; int g0, Ksrc;
  if(b < nbig)          { srcp = next_h; dstp = Bg;    g0 = b * 256;               Ksrc = K;   }
  else if(b < nbig + 16){ srcp = W_conv; dstp = Wcg;   g0 = (b - nbig) * 256;      Ksrc = 128; }
  else if(b < nbig + 32){ srcp = W_fus;  dstp = Wfg;   g0 = (b - nbig - 16) * 256; Ksrc = 128; }
  else                  { srcp = cat_W;  dstp = catWg; g0 = (b - nbig - 32) * 256; Ksrc = 256; }
  int g = g0 + threadIdx.x;
  int k8 = g >> 7, col = g & 127;
  bf16 tmp[8];
  #pragma unroll
  for(int j = 0; j < 8; j++){
    int k = k8 * 8 + j;
    tmp[j] = (k < Ksrc) ? (bf16)srcp[(size_t)k * LG_D + col] : (bf16)0.f;
  }
  *(bf16x8*)(dstp + (size_t)g * 8) = *(bf16x8*)tmp;
}

// ---------------- BM=32 BK=32 depth-2 copy-free pipelined MFMA GEMM body ----------------
// 128 thr = 2 waves; wave w owns 16 rows x 128 cols. 3 LDS B-buffers (8KB each),
// 3 statically-indexed A-register slots, explicit GB_STEP(0/1/2) rotation ->
// NO loop-carried register copies -> the only wait is counted vmcnt for the
// set issued TWO steps ago. One raw s_barrier per step; stage issued AFTER
// the barrier (its target buffer was read at t-1; barrier t makes that safe).
// ASRC 0: f32 A (SK partials summed)   1: bf16 A
// EPI 0: f32 partial to Cf + gy*partStride
//     1: *= rsqrt(cnt[r]+1) -> bf16 Cb[r*256 + yoff + col]
//     2: += bias, fused LayerNorm -> f32 Cf[r*128 + col]

#define GB_LOADA(G, S) \
    do{ if(ASRC == 1) loadAb((G), ab[S]); \
        else if(SK == 2) loadA2((G), au0[S], au1[S], av0[S], av1[S]); \
        else loadA1((G), au0[S], au1[S]); }while(0)

#define GB_WAITV() \
    do{ if(ASRC == 1)      asm volatile("s_waitcnt vmcnt(5)" ::: "memory"); \
        else if(SK == 2)   asm volatile("s_waitcnt vmcnt(8)" ::: "memory"); \
        else               asm volatile("s_waitcnt vmcnt(6)" ::: "memory"); }while(0)

#define GB_STEP(S) \
  { \
    GB_WAITV(); \
    __builtin_amdgcn_s_barrier(); \
    __builtin_amdgcn_sched_barrier(0); \
    stageB(step0 + t + 2, (S + 2) % 3); \
    GB_LOADA(step0 + t + 2, (S + 2) % 3); \
    bf16x8 af; \
    if(ASRC == 1) af = ab[S]; \
    else if(SK == 2){ \
      f32x4 s0, s1; \
      s0.x=au0[S].x+av0[S].x; s0.y=au0[S].y+av0[S].y; s0.z=au0[S].z+av0[S].z; s0.w=au0[S].w+av0[S].w; \
      s1.x=au1[S].x+av1[S].x; s1.y=au1[S].y+av1[S].y; s1.z=au1[S].z+av1[S].z; s1.w=au1[S].w+av1[S].w; \
      af = cvt(s0, s1); \
    } else af = cvt(au0[S], au1[S]); \
    const bf16* bp = &Bs[S][(lg * 128 + l16) * 8]; \
    _Pragma("unroll") \
    for(int ni = 0; ni < 8; ni++){ \
      bf16x8 bq = *(const bf16x8*)(bp + ni * 128); \
      acc[ni] = __builtin_amdgcn_mfma_f32_16x16x32_bf16(af, bq, acc[ni], 0, 0, 0); \
    } \
    t++; \
    if(t == nt) goto kdone; \
  }

template<int ASRC, int EPI, int SK>
__device__ __forceinline__ void gemm_body(bf16 (*Bs)[4096], int gx, int gy,
    const float* __restrict__ Af, const bf16* __restrict__ Abf,
    const bf16* __restrict__ Bg,
    float* __restrict__ Cf, bf16* __restrict__ Cb,
    int M, int K, int spc, int TOT, size_t partStride, int yoff,
    const int* __restrict__ cntdeg, const float* __restrict__ bias,
    const float* __restrict__ lng, const float* __restrict__ lnb)
{
  const int tid  = threadIdx.x;
  const int lane = tid & 63, w = tid >> 6;
  const int l16  = lane & 15, lg = lane >> 4;
  const int row0 = gx * 32;
  const int step0 = gy * spc;
  int nt = TOT - step0; if(nt > spc) nt = spc;

  f32x4 acc[8] = {};

  int r = row0 + w * 16 + l16; if(r > M - 1) r = M - 1;   // store is guarded
  const float* Apf = Af  ? Af  + (size_t)r * K + lg * 8 : nullptr;
  const bf16*  Apb = Abf ? Abf + (size_t)r * K + lg * 8 : nullptr;

  f32x4 au0[3], au1[3], av0[3], av1[3];
  bf16x8 ab[3];

  auto stageB = [&](int g, int buf){
    const bf16* sp = Bg + ((size_t)g * 512 + tid) * 8;
    #pragma unroll
    for(int i = 0; i < 4; i++)
      gload_lds16(sp + i * 1024, &Bs[buf][(i * 128 + w * 64) * 8]);
  };
  auto aoff = [&](int g){
    int kk = g * 32;
    return (kk + lg * 8 < K) ? kk : 0;    // OOB k-slots hit zero-B granules
  };
  auto loadA1 = [&](int g, f32x4& u0, f32x4& u1){
    int off = aoff(g);
    u0 = *(const f32x4*)(Apf + off);
    u1 = *(const f32x4*)(Apf + off + 4);
  };
  auto loadA2 = [&](int g, f32x4& u0, f32x4& u1, f32x4& v0, f32x4& v1){
    int off = aoff(g);
    u0 = *(const f32x4*)(Apf + off);
    u1 = *(const f32x4*)(Apf + off + 4);
    v0 = *(const f32x4*)(Apf + partStride + off);
    v1 = *(const f32x4*)(Apf + partStride + off + 4);
  };
  auto loadAb = [&](int g, bf16x8& b){
    int off = aoff(g);
    b = *(const bf16x8*)(Apb + off);
  };
  auto cvt = [&](const f32x4& u0, const f32x4& u1){
    bf16x8 a;
    a[0]=(bf16)u0.x; a[1]=(bf16)u0.y; a[2]=(bf16)u0.z; a[3]=(bf16)u0.w;
    a[4]=(bf16)u1.x; a[5]=(bf16)u1.y; a[6]=(bf16)u1.z; a[7]=(bf16)u1.w;
    return a;
  };

  // prologue: issue sets for tiles step0, step0+1 into slots 0,1
  stageB(step0, 0);     GB_LOADA(step0, 0);
  stageB(step0 + 1, 1); GB_LOADA(step0 + 1, 1);

  {
    int t = 0;
    while(true){
      GB_STEP(0)
      GB_STEP(1)
      GB_STEP(2)
    }
  }
kdone:

  // ---- epilogues (C/D layout: col = l16, row = lg*4 + j; m89-verified) ----
  if(EPI == 0){
    float* Co = Cf + (size_t)gy * partStride;
    #pragma unroll
    for(int j = 0; j < 4; j++){
      int rr = row0 + w * 16 + lg * 4 + j;
      if(rr < M){
        #pragma unroll
        for(int ni = 0; ni < 8; ni++)
          Co[(size_t)rr * LG_D + ni * 16 + l16] = acc[ni][j];
      }
    }
  } else if(EPI == 1){
    #pragma unroll
    for(int j = 0; j < 4; j++){
      int rr = row0 + w * 16 + lg * 4 + j;
      if(rr < M){
        float sc = rsqrtf((float)(cntdeg[rr] + 1));
        #pragma unroll
        for(int ni = 0; ni < 8; ni++)
          Cb[(size_t)rr * 256 + yoff + ni * 16 + l16] = (bf16)(acc[ni][j] * sc);
      }
    }
  } else {
    float gg[8], bbta[8], bs[8];
    #pragma unroll
    for(int ni = 0; ni < 8; ni++){
      int col = ni * 16 + l16;
      gg[ni] = lng[col]; bbta[ni] = lnb[col]; bs[ni] = bias[col];
    }
    #pragma unroll
    for(int j = 0; j < 4; j++){
      int rr = row0 + w * 16 + lg * 4 + j;
      float v[8]; float s1 = 0.f, s2 = 0.f;
      #pragma unroll
      for(int ni = 0; ni < 8; ni++){
        v[ni] = acc[ni][j] + bs[ni];
        s1 += v[ni]; s2 += v[ni] * v[ni];
      }
      #pragma unroll
      for(int off = 1; off < 16; off <<= 1){
        s1 += __shfl_xor(s1, off, 64);
        s2 += __shfl_xor(s2, off, 64);
      }
      float mu  = s1 * (1.f / 128.f);
      float inv = rsqrtf(s2 * (1.f / 128.f) - mu * mu + 1e-5f);
      if(rr < M){
        #pragma unroll
        for(int ni = 0; ni < 8; ni++)
          Cf[(size_t)rr * LG_D + ni * 16 + l16] = (v[ni] - mu) * inv * gg[ni] + bbta[ni];
      }
    }
  }
}

// ---------------- 128-thread exclusive scan (rides inside the K2 dispatch) ----------------
// Writes q[i] = exclusive prefix of cnt (= CSR start of row i). Scatter then
// destructively bumps q[d] to end_d; spmm reads beg = q[row-1], end = q[row].
__device__ void scan_body(const int* __restrict__ cnt, int* __restrict__ q, int n, int* sh){
  const int tid = threadIdx.x;
  const int lane = tid & 63, wid = tid >> 6;
  int carry = 0;
  for(int base = 0; base < n; base += 128){
    int i = base + tid;
    int v = (i < n) ? cnt[i] : 0;
    int x = v;
    #pragma unroll
    for(int off = 1; off < 64; off <<= 1){
      int y = __shfl_up(x, off, 64);
      if(lane >= off) x += y;
    }
    if(lane == 63) sh[wid] = x;
    __syncthreads();
    int w0 = sh[0], w1 = sh[1];
    int excl = x - v + (wid ? w0 : 0) + carry;
    if(i < n) q[i] = excl;
    carry += w0 + w1;
    __syncthreads();
  }
}

// ---------------- K2: curr_inc GEMM (split-K x2) + scan as last block ----------------
__global__ __launch_bounds__(128, 3) void k2_inc_scan(
    const float* __restrict__ Af, const bf16* __restrict__ Bg, float* __restrict__ Cf,
    int M, int K, int spc, int TOT, size_t partStride, int gm,
    const int* __restrict__ cnt_in, int* __restrict__ q, int n){
  __shared__ bf16 Bs[3][4096];
  int bx = blockIdx.x;
  if(bx >= 2 * gm){
    scan_body(cnt_in, q, n, (int*)&Bs[0][0]);
    return;
  }
  gemm_body<0, 0, 1>(Bs, bx % gm, bx / gm, Af, nullptr, Bg, Cf, nullptr,
                     M, K, spc, TOT, partStride, 0, nullptr, nullptr, nullptr, nullptr);
}

// ---------------- K3: both H-halves (4a: curr_h@Wc, 4b: (part0+part1)@Wf) + scatter tail ----------------
__global__ __launch_bounds__(128, 3) void k3_h_scatter(
    const float* __restrict__ curr_h, const float* __restrict__ part,
    const bf16* __restrict__ Wcg, const bf16* __restrict__ Wfg,
    bf16* __restrict__ H, int M, size_t pstride, const int* __restrict__ cnt_out, int gm,
    const int* __restrict__ src, const int* __restrict__ dst,
    int* __restrict__ q, int* __restrict__ csr, int E){
  __shared__ bf16 Bs[3][4096];
  int bx = blockIdx.x;
  if(bx >= 2 * gm){
    int e = (bx - 2 * gm) * 128 + threadIdx.x;
    if(e < E){
      int d = dst[e];
      int pos = atomicAdd(&q[d], 1);   // q[d]: start -> end as edges land
      csr[pos] = src[e];
    }
    return;
  }
  if(bx < gm)
    gemm_body<0, 1, 1>(Bs, bx, 0, curr_h, nullptr, Wcg, nullptr, H,
                       M, 128, 4, 4, 0, 0, cnt_out, nullptr, nullptr, nullptr);
  else
    gemm_body<0, 1, 2>(Bs, bx - gm, 0, part, nullptr, Wfg, nullptr, H,
                       M, 128, 4, 4, pstride, 128, cnt_out, nullptr, nullptr, nullptr);
}

// ---------------- K5: final GEMM + fused LayerNorm ----------------
__global__ __launch_bounds__(128, 3) void k5_cat_ln(
    const bf16* __restrict__ V, const bf16* __restrict__ Wg, float* __restrict__ res,
    int M, int K,
    const float* __restrict__ bias, const float* __restrict__ lng, const float* __restrict__ lnb){
  __shared__ bf16 Bs[3][4096];
  gemm_body<1, 2, 1>(Bs, blockIdx.x, 0, nullptr, V, Wg, res, nullptr,
                     M, K, 8, 8, 0, 0, nullptr, bias, lng, lnb);
}

// ---------------- fused SpMM (1 wave per row, bf16x4/lane, 2-deep gather pipeline) ----------------
__global__ __launch_bounds__(256) void spmm_fuse_kernel(const bf16* __restrict__ H,
    const int* __restrict__ q, const int* __restrict__ csr,
    const float* __restrict__ b_conv, const float* __restrict__ conv_w,
    const float* __restrict__ b_fus,  const float* __restrict__ td_w,
    bf16* __restrict__ V, int M){
  const int lane = threadIdx.x & 63;
  const int row  = blockIdx.x * 4 + (threadIdx.x >> 6);
  if(row >= M) return;
  const int end = q[row];
  const int beg = row ? q[row - 1] : 0;
  const int n   = end - beg;

  float acc[4];
  {
    bf16x4 h = *(const bf16x4*)(H + (size_t)row * 256 + lane * 4);   // self-loop
    #pragma unroll
    for(int j = 0; j < 4; j++) acc[j] = (float)h[j];
  }
  // rolling 2-deep window: register renaming keeps 2 gathers in flight
  bf16x4 f0, f1;
  if(n > 0) f0 = *(const bf16x4*)(H + (size_t)csr[beg] * 256 + lane * 4);
  if(n > 1) f1 = *(const bf16x4*)(H + (size_t)csr[beg + 1] * 256 + lane * 4);
  int i = 0;
  for(; i + 2 < n; i++){
    bf16x4 c = f0; f0 = f1;
    f1 = *(const bf16x4*)(H + (size_t)csr[beg + i + 2] * 256 + lane * 4);
    #pragma unroll
    for(int j = 0; j < 4; j++) acc[j] += (float)c[j];
  }
  if(i < n){
    #pragma unroll
    for(int j = 0; j < 4; j++) acc[j] += (float)f0[j];
    i++;
  }
  if(i < n){
    #pragma unroll
    for(int j = 0; j < 4; j++) acc[j] += (float)f1[j];
  }

  float rs = rsqrtf((float)(n + 1));                // deg_in
  const bool low = lane < 32;
  const int ci = low ? lane * 4 : (lane - 32) * 4;
  const float* bp_ = low ? b_conv : b_fus;
  const float* wp_ = low ? conv_w : td_w;
  float mine[4], other[4];
  #pragma unroll
  for(int j = 0; j < 4; j++)
    mine[j] = (acc[j] * rs + bp_[ci + j]) * wp_[ci + j];
  #pragma unroll
  for(int j = 0; j < 4; j++)
    other[j] = __shfl_xor(mine[j], 32, 64);
  if(low){
    bf16x4 o1, o2;
    #pragma unroll
    for(int j = 0; j < 4; j++){
      float cs = mine[j], td = other[j];
      o1[j] = (bf16)(fmaxf(cs, 0.f) + fmaxf(td, 0.f));
      o2[j] = (bf16)(cs + td);
    }
    *(bf16x4*)(V + (size_t)row * 256 + lane * 4)       = o1;
    *(bf16x4*)(V + (size_t)row * 256 + 128 + lane * 4) = o2;
  }
}

// ---------------- launch ----------------

extern "C" void kernel_launch(void* const* d_in, const int* in_sizes, int n_in,
                              void* d_out, int out_size, void* d_ws, size_t ws_size,
                              hipStream_t stream){
  const float* curr_h   = (const float*)d_in[0];
  const float* next_h   = (const float*)d_in[1];
  const float* curr_inc = (const float*)d_in[2];
  const int*   src      = (const int*)d_in[3];
  const int*   dst      = (const int*)d_in[4];
  const float* W_conv   = (const float*)d_in[5];
  const float* b_conv   = (const float*)d_in[6];
  const float* W_fus    = (const float*)d_in[7];
  const float* b_fus    = (const float*)d_in[8];
  const float* conv_w   = (const float*)d_in[9];
  const float* td_w     = (const float*)d_in[10];
  const float* cat_W    = (const float*)d_in[11];
  const float* cat_b    = (const float*)d_in[12];
  const float* ln_g     = (const float*)d_in[13];
  const float* ln_b     = (const float*)d_in[14];

  const int D    = LG_D;
  const int M    = in_sizes[0] / D;      // 20000
  const int Kinc = in_sizes[1] / D;      // 10000
  const int E    = in_sizes[3];          // 320000
  const int K2   = in_sizes[11] / D;     // 256

  const int TOT1    = (Kinc + 31) / 32;  // 313 BK=32 tiles
  const int SPC1    = (TOT1 + 1) / 2;    // 157 tiles/chunk (split-K x2)
  const int K8ALLOC = (TOT1 + 2) * 4;    // 1260 k8-groups (incl. prefetch-overrun pad)
  const int NBIG    = (K8ALLOC * 128) / 256;  // 630 granulate blocks for Bg

  // workspace carve (256B aligned); ws ~3.2GB
  char* p = (char*)d_ws;
  auto alloc = [&](size_t bytes){ char* q = p; p += (bytes + 255) & ~(size_t)255; return q; };
  float* part   = (float*)alloc((size_t)2 * M * D * 4);
  bf16*  H      = (bf16*) alloc((size_t)M * 256 * 2);
  bf16*  V      = (bf16*) alloc((size_t)M * 256 * 2);
  bf16*  Bg     = (bf16*) alloc((size_t)K8ALLOC * 128 * 16);
  bf16*  Wcg    = (bf16*) alloc((size_t)32 * 128 * 16);    // k8 pad to 32
  bf16*  Wfg    = (bf16*) alloc((size_t)32 * 128 * 16);
  bf16*  catWg  = (bf16*) alloc((size_t)48 * 128 * 16);    // k8 pad to 48
  int*   cnts   = (int*)  alloc((size_t)2 * M * 4);        // cnt_in | cnt_out
  int*   q      = (int*)  alloc((size_t)M * 4);            // CSR starts -> ends
  int*   csr    = (int*)  alloc((size_t)E * 4);
  int* cnt_in  = cnts;
  int* cnt_out = cnts + M;
  (void)ws_size; (void)n_in; (void)out_size;

  float* res = (float*)d_out;
  const int gm = (M + 31) / 32;          // 625
  const size_t pstride = (size_t)M * D;

  // 1. zero degree counters (one dispatch, contiguous)
  zero_kernel<<<(2 * M + 255) / 256, 256, 0, stream>>>(cnts, 2 * M);

  // 2. granulate all B matrices + edge histogram (merged, independent work)
  k1_gran_hist<<<NBIG + 56 + (E + 255) / 256, 256, 0, stream>>>(
      next_h, W_conv, W_fus, cat_W, Bg, Wcg, Wfg, catWg, Kinc, NBIG,
      src, dst, cnt_out, cnt_in, E);

  // 3. part[y] = curr_inc @ B^T over K-chunk y  (800 MB stream, split-K x2,
  //    1250 blocks co-resident, depth-2 copy-free pipeline) + scan rides as
  //    block 2*gm (hidden under the ~140us BW-bound GEMM)
  k2_inc_scan<<<2 * gm + 1, 128, 0, stream>>>(
      curr_inc, Bg, part, M, Kinc, SPC1, TOT1, pstride, gm, cnt_in, q, M);

  // 4. H[:,0:128] = (curr_h @ W_conv) * rsqrt(deg_out)   [blocks 0..gm)
  //    H[:,128:256] = ((part0+part1) @ W_fus) * rsqrt(deg_out) [blocks gm..2gm)
  //    + CSR scatter as tail blocks (needs q from scan, destroys q into ends)
  k3_h_scatter<<<2 * gm + (E + 127) / 128, 128, 0, stream>>>(
      curr_h, part, Wcg, Wfg, H, M, pstride, cnt_out, gm,
      src, dst, q, csr, E);

  // 5. SpMM + normalize + bias + channel weights + relu/concat -> V[M][256] bf16
  spmm_fuse_kernel<<<(M + 3) / 4, 256, 0, stream>>>(H, q, csr,
                                          b_conv, conv_w, b_fus, td_w, V, M);

  // 6+7. res = LayerNorm(V @ cat_W + cat_b)  (LN fused into epilogue)
  k5_cat_ln<<<gm, 128, 0, stream>>>(V, catWg, res, M, K2, cat_b, ln_g, ln_b);
}